// Round 6
// baseline (1356.205 us; speedup 1.0000x reference)
//
#include <hip/hip_runtime.h>

#define NN 114688      // nodes
#define NE 917504      // edges
#define NBATCH 8192    // graphs
#define GSZ 14         // nodes per graph
#define NCLS 10
#define EPSB 1e-5f
#define NSCAN 112      // NN / 1024

typedef unsigned short u16;
typedef short bf16x8 __attribute__((ext_vector_type(8)));
typedef float f32x4 __attribute__((ext_vector_type(4)));
typedef _Float16 h8t __attribute__((ext_vector_type(8)));
typedef unsigned short u16x8 __attribute__((ext_vector_type(8)));

__device__ __forceinline__ float bf2f(u16 u) {
    union { unsigned int i; float f; } v; v.i = ((unsigned int)u) << 16; return v.f;
}
__device__ __forceinline__ u16 f2bf(float f) {
    union { float f; unsigned int i; } v; v.f = f;
    unsigned int i = v.i;
    unsigned int r = i + 0x7FFFu + ((i >> 16) & 1u);   // RNE
    return (u16)(r >> 16);
}
__device__ __forceinline__ void splitbf(float y, u16& h, u16& l) {
    h = f2bf(y);
    l = f2bf(y - bf2f(h));
}

// ---------------- graph preprocessing ----------------
__global__ __launch_bounds__(256) void k_hist(const int* __restrict__ ei, int* __restrict__ counts) {
    int e = blockIdx.x * 256 + threadIdx.x;
    atomicAdd(&counts[ei[NE + e]], 1);
}

__global__ __launch_bounds__(256) void k_scan1(const int* __restrict__ counts, int* __restrict__ bsum) {
    __shared__ int red[256];
    int tid = threadIdx.x;
    int base = blockIdx.x * 1024 + tid * 4;
    int s = counts[base] + counts[base + 1] + counts[base + 2] + counts[base + 3];
    red[tid] = s; __syncthreads();
    for (int o = 128; o > 0; o >>= 1) {
        if (tid < o) red[tid] += red[tid + o];
        __syncthreads();
    }
    if (tid == 0) bsum[blockIdx.x] = red[0];
}

__global__ void k_scan2(int* bsum, int* offs) {
    if (threadIdx.x == 0) {
        int run = 0;
        for (int i = 0; i < NSCAN; i++) { int t = bsum[i]; bsum[i] = run; run += t; }
        offs[NN] = run;
    }
}

__global__ __launch_bounds__(256) void k_scan3(const int* __restrict__ counts, const int* __restrict__ bsum,
                                               int* __restrict__ offs) {
    __shared__ int ss[256];
    int tid = threadIdx.x;
    int base = blockIdx.x * 1024 + tid * 4;
    int v0 = counts[base], v1 = counts[base + 1], v2 = counts[base + 2], v3 = counts[base + 3];
    int ts = v0 + v1 + v2 + v3;
    ss[tid] = ts; __syncthreads();
    for (int o = 1; o < 256; o <<= 1) {
        int add = (tid >= o) ? ss[tid - o] : 0;
        __syncthreads();
        ss[tid] += add;
        __syncthreads();
    }
    int excl = ss[tid] - ts + bsum[blockIdx.x];
    offs[base] = excl;
    offs[base + 1] = excl + v0;
    offs[base + 2] = excl + v0 + v1;
    offs[base + 3] = excl + v0 + v1 + v2;
}

__global__ __launch_bounds__(256) void k_dis_cursor(const int* __restrict__ counts, const int* __restrict__ offs,
                                                    float* __restrict__ dis, int* __restrict__ cursor) {
    int n = blockIdx.x * 256 + threadIdx.x;
    dis[n] = rsqrtf((float)counts[n] + 1.0f);
    cursor[n] = offs[n];
}

__global__ __launch_bounds__(256) void k_scatter(const int* __restrict__ ei, int* __restrict__ cursor,
                                                 int* __restrict__ srcs, float* __restrict__ sd,
                                                 const float* __restrict__ dis) {
    int e = blockIdx.x * 256 + threadIdx.x;
    int d = ei[NE + e], s = ei[e];
    int p = atomicAdd(&cursor[d], 1);
    srcs[p] = s;
    sd[p] = dis[s];
}

// transpose + split fp32 W[K,F] -> bf16 Wh/Wl [F,K] (no affine; layer 1)
__global__ __launch_bounds__(256) void k_tsplit(const float* __restrict__ Wsrc,
                                                u16* __restrict__ Wh, u16* __restrict__ Wl,
                                                int K, int F) {
    int i = blockIdx.x * 256 + threadIdx.x;
    if (i < K * F) {
        int k = i / F, f = i % F;
        u16 h, l; splitbf(Wsrc[i], h, l);
        Wh[f * K + k] = h;
        Wl[f * K + k] = l;
    }
}

// fold BN affine into weights: Wh/Wl[f,k] = split(sc[k]*W[k,f]), c2[f] = sum_k sh[k]*W[k,f]
__global__ void k_wfold(const float* __restrict__ W, const float* __restrict__ sc,
                        const float* __restrict__ sh, u16* __restrict__ Wh, u16* __restrict__ Wl,
                        float* __restrict__ c2, int K, int F) {
    int f = threadIdx.x;
    if (f >= F) return;
    float acc = 0.f;
    for (int k = 0; k < K; k++) {
        float w = W[k * F + f];
        u16 h, l; splitbf(sc[k] * w, h, l);
        Wh[f * K + k] = h;
        Wl[f * K + k] = l;
        acc += sh[k] * w;
    }
    c2[f] = acc;
}

// ---------------- split MFMA GEMM: C = A @ W' + c2, fp32-grade via bf16x3 ----------------
// AFP32: A is fp32 (layer 1, split at stage). Else A is two exact bf16 planes Ahi/Alo [N][K].
// W pre-split (+BN-folded) bf16 hi/lo [Fout][K]. C2: init acc with per-column constant. C fp16.
template<int BM, int BN, int WCOLS, bool AFP32, bool C2>
__global__ __launch_bounds__(256) void k_gemm(
    const float* __restrict__ Af, const u16* __restrict__ Ahi, const u16* __restrict__ Alo,
    const u16* __restrict__ Wh, const u16* __restrict__ Wl,
    _Float16* __restrict__ C, const int K, const int Fout, const float* __restrict__ c2)
{
    constexpr int AST = 40;                // 32 + 8 pad
    __shared__ u16 Ah[BM][AST], Al[BM][AST];
    __shared__ u16 Bh[BN][AST], Bl[BN][AST];

    const int tid = threadIdx.x;
    const int row0 = blockIdx.y * BM;
    const int col0 = blockIdx.x * BN;

    const int wave = tid >> 6, lane = tid & 63;
    const int mb = (wave / WCOLS) * 64;
    const int nb = (wave % WCOLS) * 64;
    const int lm = lane & 15;
    const int lk = (lane >> 4) * 8;
    const int cb = col0 + nb + lm;

    float c2v[4] = {0.f, 0.f, 0.f, 0.f};
    if constexpr (C2) {
#pragma unroll
        for (int ni = 0; ni < 4; ni++) c2v[ni] = c2[cb + ni * 16];
    }

    f32x4 acc[4][4];
#pragma unroll
    for (int i = 0; i < 4; i++)
#pragma unroll
        for (int j = 0; j < 4; j++)
#pragma unroll
            for (int r = 0; r < 4; r++) acc[i][j][r] = c2v[j];

    const int stg_r = tid >> 3;        // 0..31
    const int stg_c = (tid & 7) * 4;   // 0,4..28

    for (int k0 = 0; k0 < K; k0 += 32) {
        __syncthreads();
#pragma unroll
        for (int p = 0; p < BM / 32; p++) {
            const int r = p * 32 + stg_r;
            if constexpr (AFP32) {
                const float4 v = *(const float4*)(Af + (size_t)(row0 + r) * K + k0 + stg_c);
                float y[4] = {v.x, v.y, v.z, v.w};
                ushort4 hv, lv;
#pragma unroll
                for (int q = 0; q < 4; q++) splitbf(y[q], ((u16*)&hv)[q], ((u16*)&lv)[q]);
                *(ushort4*)&Ah[r][stg_c] = hv;
                *(ushort4*)&Al[r][stg_c] = lv;
            } else {
                *(ushort4*)&Ah[r][stg_c] = *(const ushort4*)(Ahi + (size_t)(row0 + r) * K + k0 + stg_c);
                *(ushort4*)&Al[r][stg_c] = *(const ushort4*)(Alo + (size_t)(row0 + r) * K + k0 + stg_c);
            }
        }
#pragma unroll
        for (int p = 0; p < BN / 32; p++) {
            const int n = p * 32 + stg_r;
            *(ushort4*)&Bh[n][stg_c] = *(const ushort4*)(Wh + (size_t)(col0 + n) * K + k0 + stg_c);
            *(ushort4*)&Bl[n][stg_c] = *(const ushort4*)(Wl + (size_t)(col0 + n) * K + k0 + stg_c);
        }
        __syncthreads();

        bf16x8 ah[4], al[4], bh[4], bl[4];
#pragma unroll
        for (int mi = 0; mi < 4; mi++) {
            ah[mi] = *(const bf16x8*)&Ah[mb + mi * 16 + lm][lk];
            al[mi] = *(const bf16x8*)&Al[mb + mi * 16 + lm][lk];
        }
#pragma unroll
        for (int ni = 0; ni < 4; ni++) {
            bh[ni] = *(const bf16x8*)&Bh[nb + ni * 16 + lm][lk];
            bl[ni] = *(const bf16x8*)&Bl[nb + ni * 16 + lm][lk];
        }
#pragma unroll
        for (int mi = 0; mi < 4; mi++)
#pragma unroll
            for (int ni = 0; ni < 4; ni++) {
                acc[mi][ni] = __builtin_amdgcn_mfma_f32_16x16x32_bf16(al[mi], bh[ni], acc[mi][ni], 0, 0, 0);
                acc[mi][ni] = __builtin_amdgcn_mfma_f32_16x16x32_bf16(ah[mi], bl[ni], acc[mi][ni], 0, 0, 0);
                acc[mi][ni] = __builtin_amdgcn_mfma_f32_16x16x32_bf16(ah[mi], bh[ni], acc[mi][ni], 0, 0, 0);
            }
    }

    const int rb = row0 + mb + (lane >> 4) * 4;
#pragma unroll
    for (int mi = 0; mi < 4; mi++)
#pragma unroll
        for (int ni = 0; ni < 4; ni++)
#pragma unroll
            for (int r = 0; r < 4; r++)
                C[(size_t)(rb + mi * 16 + r) * Fout + cb + ni * 16] = (_Float16)acc[mi][ni][r];
}

// ---------------- aggregation: t = relu(dn*sum(sd_e*h_s) + dn^2*h_n + b), fused BN stats --------
// h fp16 [N][CH]; t written as exact bf16 hi/lo planes [N][CH]. Edge-parallel sub-wavelets,
// 16 ch/lane (32 B); butterfly shfl_xor merges partials. Stats on the exact fp32 value.
template<int CH>
__global__ __launch_bounds__(256) void k_agg(
    const _Float16* __restrict__ h, u16* __restrict__ thi, u16* __restrict__ tlo,
    const float* __restrict__ bias,
    const int* __restrict__ off, const int* __restrict__ srcs, const float* __restrict__ sd,
    const float* __restrict__ dis, float* __restrict__ statS, float* __restrict__ statQ)
{
    constexpr int ECH = 16;            // channels per lane (32B fp16)
    constexpr int LPG = CH / ECH;      // lanes per edge-group
    constexpr int NSUB = 64 / LPG;     // edges in flight per wave
    __shared__ float redS[CH], redQ[CH];
    const int tid = threadIdx.x;
    for (int i = tid; i < CH; i += 256) { redS[i] = 0.f; redQ[i] = 0.f; }
    __syncthreads();

    const int lane = tid & 63;
    const int sub = lane / LPG;
    const int c = (lane % LPG) * ECH;
    const int wid = (blockIdx.x * 256 + tid) >> 6;
    const int nw = (gridDim.x * 256) >> 6;

    float bs[ECH], bq[ECH], bv[ECH];
#pragma unroll
    for (int v = 0; v < ECH; v++) { bs[v] = 0.f; bq[v] = 0.f; bv[v] = bias[c + v]; }

    for (int n = wid; n < NN; n += nw) {
        const int p0 = off[n], p1 = off[n + 1];
        float a[ECH];
#pragma unroll
        for (int v = 0; v < ECH; v++) a[v] = 0.f;

        int p = p0 + sub;
        int s = 0; float w = 0.f;
        if (p < p1) { s = srcs[p]; w = sd[p]; }
        while (p < p1) {
            const int pn = p + NSUB;
            int s2 = 0; float w2 = 0.f;
            if (pn < p1) { s2 = srcs[pn]; w2 = sd[pn]; }   // prefetch next edge
            const _Float16* hr = h + (size_t)s * CH + c;
            h8t hv0 = *(const h8t*)hr;
            h8t hv1 = *(const h8t*)(hr + 8);
#pragma unroll
            for (int v = 0; v < 8; v++) { a[v] += w * (float)hv0[v]; a[v + 8] += w * (float)hv1[v]; }
            s = s2; w = w2; p = pn;
        }
        // merge edge-group partials across sub-wavelets
#pragma unroll
        for (int o = LPG; o < 64; o <<= 1) {
#pragma unroll
            for (int v = 0; v < ECH; v++) a[v] += __shfl_xor(a[v], o);
        }
        if (sub == 0) {
            const float dn = dis[n];
            const float dn2 = dn * dn;
            const _Float16* hr = h + (size_t)n * CH + c;
            h8t hn0 = *(const h8t*)hr;
            h8t hn1 = *(const h8t*)(hr + 8);
            float o16[ECH];
#pragma unroll
            for (int v = 0; v < 8; v++) {
                o16[v] = fmaxf(dn * a[v] + dn2 * (float)hn0[v] + bv[v], 0.f);
                o16[v + 8] = fmaxf(dn * a[v + 8] + dn2 * (float)hn1[v] + bv[v + 8], 0.f);
            }
            u16x8 hv0, lv0, hv1, lv1;
#pragma unroll
            for (int v = 0; v < 8; v++) {
                splitbf(o16[v], ((u16*)&hv0)[v], ((u16*)&lv0)[v]);
                splitbf(o16[v + 8], ((u16*)&hv1)[v], ((u16*)&lv1)[v]);
                bs[v] += o16[v]; bq[v] += o16[v] * o16[v];
                bs[v + 8] += o16[v + 8]; bq[v + 8] += o16[v + 8] * o16[v + 8];
            }
            u16* th = thi + (size_t)n * CH + c;
            u16* tl = tlo + (size_t)n * CH + c;
            *(u16x8*)th = hv0; *(u16x8*)(th + 8) = hv1;
            *(u16x8*)tl = lv0; *(u16x8*)(tl + 8) = lv1;
        }
    }
    if (sub == 0) {
#pragma unroll
        for (int v = 0; v < ECH; v++) { atomicAdd(&redS[c + v], bs[v]); atomicAdd(&redQ[c + v], bq[v]); }
    }
    __syncthreads();
    for (int i = tid; i < CH; i += 256) { atomicAdd(&statS[i], redS[i]); atomicAdd(&statQ[i], redQ[i]); }
}

// ---------------- BN stats -> scale/shift ----------------
__global__ void k_bnpar(const float* __restrict__ S, const float* __restrict__ Q,
                        const float* __restrict__ g, const float* __restrict__ b,
                        float* __restrict__ sc, float* __restrict__ sh, int F) {
    int c = threadIdx.x;
    if (c >= F) return;
    const float invn = 1.0f / (float)NN;
    float mean = S[c] * invn;
    float var = Q[c] * invn - mean * mean;
    float s = g[c] * rsqrtf(fmaxf(var, 0.f) + EPSB);
    sc[c] = s;
    sh[c] = b[c] - mean * s;
}

// ---------------- small dense layer: C[N,F] = affine(A)[N,K] @ W[K,F] (+bias) ----------------
// A = bf16 hi/lo planes, C fp16, fp32 compute.
template<int K, int F, bool BIAS>
__global__ __launch_bounds__(256) void k_smm(
    const u16* __restrict__ Ahi, const u16* __restrict__ Alo,
    const float* __restrict__ Wf, const float* __restrict__ bias,
    _Float16* __restrict__ C, const float* __restrict__ sc, const float* __restrict__ sh)
{
    __shared__ float Wl[K * F];
    __shared__ float scl[K], shl[K], bl[F];
    const int tid = threadIdx.x;
    for (int i = tid; i < K * F; i += 256) Wl[i] = Wf[i];
    if (tid < K) { scl[tid] = sc[tid]; shl[tid] = sh[tid]; }
    if (tid < F) {
        bl[tid] = 0.f;
        if constexpr (BIAS) bl[tid] = bias[tid];
    }
    __syncthreads();
    const int n = blockIdx.x * 256 + tid;
    float acc[F];
#pragma unroll
    for (int f = 0; f < F; f++) acc[f] = bl[f];
    const u16* ah = Ahi + (size_t)n * K;
    const u16* al = Alo + (size_t)n * K;
    for (int k = 0; k < K; k += 4) {
        ushort4 hv = *(const ushort4*)(ah + k);
        ushort4 lv = *(const ushort4*)(al + k);
        float y0 = (bf2f(hv.x) + bf2f(lv.x)) * scl[k] + shl[k];
        float y1 = (bf2f(hv.y) + bf2f(lv.y)) * scl[k + 1] + shl[k + 1];
        float y2 = (bf2f(hv.z) + bf2f(lv.z)) * scl[k + 2] + shl[k + 2];
        float y3 = (bf2f(hv.w) + bf2f(lv.w)) * scl[k + 3] + shl[k + 3];
#pragma unroll
        for (int f = 0; f < F; f += 4) {
            float4 w0 = *(const float4*)&Wl[k * F + f];
            float4 w1 = *(const float4*)&Wl[(k + 1) * F + f];
            float4 w2 = *(const float4*)&Wl[(k + 2) * F + f];
            float4 w3 = *(const float4*)&Wl[(k + 3) * F + f];
            acc[f + 0] += y0 * w0.x + y1 * w1.x + y2 * w2.x + y3 * w3.x;
            acc[f + 1] += y0 * w0.y + y1 * w1.y + y2 * w2.y + y3 * w3.y;
            acc[f + 2] += y0 * w0.z + y1 * w1.z + y2 * w2.z + y3 * w3.z;
            acc[f + 3] += y0 * w0.w + y1 * w1.w + y2 * w2.w + y3 * w3.w;
        }
    }
    _Float16* cr = C + (size_t)n * F;
#pragma unroll
    for (int f = 0; f < F; f++) cr[f] = (_Float16)acc[f];
}

// ---------------- per-channel stats over [NN, F] fp16 ----------------
template<int F>
__global__ __launch_bounds__(256) void k_stats16(const _Float16* __restrict__ A,
                                                 float* __restrict__ S, float* __restrict__ Q) {
    __shared__ float redS[F], redQ[F];
    const int tid = threadIdx.x;
    for (int i = tid; i < F; i += 256) { redS[i] = 0.f; redQ[i] = 0.f; }
    __syncthreads();
    const int g = blockIdx.x * 256 + tid;
    const int c = g % F;
    const int step = (gridDim.x * 256) / F;
    float s = 0.f, q = 0.f;
    for (int r = g / F; r < NN; r += step) {
        float v = (float)A[(size_t)r * F + c];
        s += v; q += v * v;
    }
    atomicAdd(&redS[c], s); atomicAdd(&redQ[c], q);
    __syncthreads();
    for (int i = tid; i < F; i += 256) { atomicAdd(&S[i], redS[i]); atomicAdd(&Q[i], redQ[i]); }
}

// stats over fp32 [NN] vector
__global__ __launch_bounds__(256) void k_stats1(const float* __restrict__ A,
                                                float* __restrict__ S, float* __restrict__ Q) {
    __shared__ float redS[1], redQ[1];
    const int tid = threadIdx.x;
    if (tid == 0) { redS[0] = 0.f; redQ[0] = 0.f; }
    __syncthreads();
    const int g = blockIdx.x * 256 + tid;
    const int step = gridDim.x * 256;
    float s = 0.f, q = 0.f;
    for (int r = g; r < NN; r += step) {
        float v = A[r];
        s += v; q += v * v;
    }
    atomicAdd(&redS[0], s); atomicAdd(&redQ[0], q);
    __syncthreads();
    if (tid == 0) { atomicAdd(&S[0], redS[0]); atomicAdd(&Q[0], redQ[0]); }
}

// ---------------- gate layer 2: g2 = relu(bn1(g1)) @ gW2 + gb2 ----------------
__global__ __launch_bounds__(256) void k_gate2(const _Float16* __restrict__ g1,
                                               const float* __restrict__ sc, const float* __restrict__ sh,
                                               const float* __restrict__ w2, const float* __restrict__ b2,
                                               float* __restrict__ g2) {
    __shared__ float wl[16], scl[16], shl[16], b2l[1];
    const int tid = threadIdx.x;
    if (tid < 16) { wl[tid] = w2[tid]; scl[tid] = sc[tid]; shl[tid] = sh[tid]; }
    if (tid == 0) b2l[0] = b2[0];
    __syncthreads();
    const int n = blockIdx.x * 256 + tid;
    const _Float16* r = g1 + (size_t)n * 16;
    float acc = b2l[0];
#pragma unroll
    for (int k = 0; k < 16; k++) {
        float y = fmaxf((float)r[k] * scl[k] + shl[k], 0.f);
        acc += y * wl[k];
    }
    g2[n] = acc;
}

// ---------------- segment softmax + pooling + FC + softmax ----------------
__global__ __launch_bounds__(256) void k_pool(const u16* __restrict__ t4hi, const u16* __restrict__ t4lo,
                                              const float* __restrict__ sc4, const float* __restrict__ sh4,
                                              const float* __restrict__ g2,
                                              const float* __restrict__ gsc2, const float* __restrict__ gsh2,
                                              const float* __restrict__ fcW, const float* __restrict__ fcb,
                                              float* __restrict__ out) {
    __shared__ float fw[32 * NCLS], fbl[NCLS], sc4l[32], sh4l[32];
    const int tid = threadIdx.x;
    for (int i = tid; i < 32 * NCLS; i += 256) fw[i] = fcW[i];
    if (tid < NCLS) fbl[tid] = fcb[tid];
    if (tid < 32) { sc4l[tid] = sc4[tid]; sh4l[tid] = sh4[tid]; }
    __syncthreads();
    const int b = blockIdx.x * 256 + tid;
    const float s2 = gsc2[0], h2 = gsh2[0];
    const int base = b * GSZ;

    float gv[GSZ];
    float m = -1e30f;
#pragma unroll
    for (int i = 0; i < GSZ; i++) {
        float v = fmaxf(g2[base + i] * s2 + h2, 0.f);
        gv[i] = v; m = fmaxf(m, v);
    }
    float ssum = 0.f;
#pragma unroll
    for (int i = 0; i < GSZ; i++) { float e = __expf(gv[i] - m); gv[i] = e; ssum += e; }
    const float inv = 1.0f / ssum;

    float pooled[32];
#pragma unroll
    for (int c = 0; c < 32; c++) pooled[c] = 0.f;
#pragma unroll
    for (int i = 0; i < GSZ; i++) {
        const float a = gv[i] * inv;
        const u16* th = t4hi + (size_t)(base + i) * 32;
        const u16* tl = t4lo + (size_t)(base + i) * 32;
#pragma unroll
        for (int c = 0; c < 32; c += 4) {
            ushort4 hv = *(const ushort4*)(th + c);
            ushort4 lv = *(const ushort4*)(tl + c);
            pooled[c + 0] += a * ((bf2f(hv.x) + bf2f(lv.x)) * sc4l[c + 0] + sh4l[c + 0]);
            pooled[c + 1] += a * ((bf2f(hv.y) + bf2f(lv.y)) * sc4l[c + 1] + sh4l[c + 1]);
            pooled[c + 2] += a * ((bf2f(hv.z) + bf2f(lv.z)) * sc4l[c + 2] + sh4l[c + 2]);
            pooled[c + 3] += a * ((bf2f(hv.w) + bf2f(lv.w)) * sc4l[c + 3] + sh4l[c + 3]);
        }
    }
    float lg[NCLS];
    float mx = -1e30f;
#pragma unroll
    for (int j = 0; j < NCLS; j++) {
        float a = fbl[j];
#pragma unroll
        for (int c = 0; c < 32; c++) a += pooled[c] * fw[c * NCLS + j];
        lg[j] = a; mx = fmaxf(mx, a);
    }
    float es = 0.f;
#pragma unroll
    for (int j = 0; j < NCLS; j++) { float e = __expf(lg[j] - mx); lg[j] = e; es += e; }
    const float iv = 1.0f / es;
#pragma unroll
    for (int j = 0; j < NCLS; j++) out[b * NCLS + j] = lg[j] * iv;
}

// ---------------- host ----------------
extern "C" void kernel_launch(void* const* d_in, const int* in_sizes, int n_in,
                              void* d_out, int out_size, void* d_ws, size_t ws_size,
                              hipStream_t stream) {
    (void)in_sizes; (void)n_in; (void)out_size; (void)ws_size;
    const float* x    = (const float*)d_in[0];
    const int*   ei   = (const int*)d_in[1];
    const float* W1   = (const float*)d_in[2];
    const float* b1   = (const float*)d_in[3];
    const float* bn1g = (const float*)d_in[4];
    const float* bn1b = (const float*)d_in[5];
    const float* W2   = (const float*)d_in[6];
    const float* b2   = (const float*)d_in[7];
    const float* bn2g = (const float*)d_in[8];
    const float* bn2b = (const float*)d_in[9];
    const float* W3   = (const float*)d_in[10];
    const float* b3   = (const float*)d_in[11];
    const float* bn3g = (const float*)d_in[12];
    const float* bn3b = (const float*)d_in[13];
    const float* W4   = (const float*)d_in[14];
    const float* b4   = (const float*)d_in[15];
    const float* bn4g = (const float*)d_in[16];
    const float* bn4b = (const float*)d_in[17];
    const float* gW1  = (const float*)d_in[18];
    const float* gb1  = (const float*)d_in[19];
    const float* gbn1g = (const float*)d_in[20];
    const float* gbn1b = (const float*)d_in[21];
    const float* gW2  = (const float*)d_in[22];
    const float* gb2  = (const float*)d_in[23];
    const float* gbn2g = (const float*)d_in[24];
    const float* gbn2b = (const float*)d_in[25];
    const float* fcW  = (const float*)d_in[26];
    const float* fcb  = (const float*)d_in[27];
    float* out = (float*)d_out;

    char* base = (char*)d_ws;
    size_t off_ = 0;
    auto carve = [&](size_t bytes) -> char* {
        char* p = base + off_;
        off_ = (off_ + bytes + 255) & ~(size_t)255;
        return p;
    };
    int*   counts = (int*)carve((size_t)NN * 4);
    float* stats  = (float*)carve(994 * 4);
    const size_t zero_bytes = off_;
    int*   offs   = (int*)carve((size_t)(NN + 1) * 4);
    int*   cursor = (int*)carve((size_t)NN * 4);
    int*   srcs   = (int*)carve((size_t)NE * 4);
    float* sd     = (float*)carve((size_t)NE * 4);
    float* dis    = (float*)carve((size_t)NN * 4);
    int*   bsum   = (int*)carve(NSCAN * 4);
    float* pars   = (float*)carve(994 * 4);
    u16*   Wt1h   = (u16*)carve(512 * 128 * 2);
    u16*   Wt1l   = (u16*)carve(512 * 128 * 2);
    u16*   Wt2h   = (u16*)carve(128 * 256 * 2);
    u16*   Wt2l   = (u16*)carve(128 * 256 * 2);
    u16*   Wt3h   = (u16*)carve(256 * 64 * 2);
    u16*   Wt3l   = (u16*)carve(256 * 64 * 2);
    float* c2_2   = (float*)carve(256 * 4);
    float* c2_3   = (float*)carve(64 * 4);
    float* g2raw  = (float*)carve((size_t)NN * 4);
    _Float16* P   = (_Float16*)carve((size_t)NN * 256 * 2);   // h buffer (fp16, up to 256 ch)
    u16*   Qhi    = (u16*)carve((size_t)NN * 128 * 2);        // t planes (<=128 ch)
    u16*   Qlo    = (u16*)carve((size_t)NN * 128 * 2);
    u16*   Rhi    = (u16*)carve((size_t)NN * 256 * 2);        // t2 planes (256 ch)
    u16*   Rlo    = (u16*)carve((size_t)NN * 256 * 2);
    // total ~245 MB (< proven-available 262 MB)

    float* S1 = stats;      float* Q1s = S1 + 128;
    float* S2 = Q1s + 128;  float* Q2s = S2 + 256;
    float* S3 = Q2s + 256;  float* Q3s = S3 + 64;
    float* S4 = Q3s + 64;   float* Q4s = S4 + 32;
    float* gS1 = Q4s + 32;  float* gQ1 = gS1 + 16;
    float* gS2 = gQ1 + 16;  float* gQ2 = gS2 + 1;

    float* sc1 = pars;      float* sh1 = sc1 + 128;
    float* sc2 = sh1 + 128; float* sh2 = sc2 + 256;
    float* sc3 = sh2 + 256; float* sh3 = sc3 + 64;
    float* sc4 = sh3 + 64;  float* sh4 = sc4 + 32;
    float* gsc1 = sh4 + 32; float* gsh1 = gsc1 + 16;
    float* gsc2 = gsh1 + 16; float* gsh2 = gsc2 + 1;

    hipMemsetAsync(d_ws, 0, zero_bytes, stream);

    k_hist<<<NE / 256, 256, 0, stream>>>(ei, counts);
    k_scan1<<<NSCAN, 256, 0, stream>>>(counts, bsum);
    k_scan2<<<1, 64, 0, stream>>>(bsum, offs);
    k_scan3<<<NSCAN, 256, 0, stream>>>(counts, bsum, offs);
    k_dis_cursor<<<NN / 256, 256, 0, stream>>>(counts, offs, dis, cursor);
    k_scatter<<<NE / 256, 256, 0, stream>>>(ei, cursor, srcs, sd, dis);
    k_tsplit<<<(512 * 128 + 255) / 256, 256, 0, stream>>>(W1, Wt1h, Wt1l, 512, 128);

    // layer 1: h1 = x @ W1 -> P (N x 128 fp16); t1 -> Q planes
    k_gemm<128, 128, 2, true, false><<<dim3(1, NN / 128), 256, 0, stream>>>(
        x, nullptr, nullptr, Wt1h, Wt1l, P, 512, 128, nullptr);
    k_agg<128><<<2048, 256, 0, stream>>>(P, Qhi, Qlo, b1, offs, srcs, sd, dis, S1, Q1s);
    k_bnpar<<<1, 256, 0, stream>>>(S1, Q1s, bn1g, bn1b, sc1, sh1, 128);

    // layer 2 (full width, BN folded into W2): h2 = t1 @ W2' + c2 -> P (N x 256); t2 -> R planes
    k_wfold<<<1, 256, 0, stream>>>(W2, sc1, sh1, Wt2h, Wt2l, c2_2, 128, 256);
    k_gemm<128, 128, 2, false, true><<<dim3(2, NN / 128), 256, 0, stream>>>(
        nullptr, Qhi, Qlo, Wt2h, Wt2l, P, 128, 256, c2_2);
    k_agg<256><<<2048, 256, 0, stream>>>(P, Rhi, Rlo, b2, offs, srcs, sd, dis, S2, Q2s);
    k_bnpar<<<1, 256, 0, stream>>>(S2, Q2s, bn2g, bn2b, sc2, sh2, 256);

    // layer 3 (BN folded into W3): h3 = t2 @ W3' + c2 -> P (N x 64); t3 -> Q planes
    k_wfold<<<1, 256, 0, stream>>>(W3, sc2, sh2, Wt3h, Wt3l, c2_3, 256, 64);
    k_gemm<256, 64, 1, false, true><<<dim3(1, NN / 256), 256, 0, stream>>>(
        nullptr, Rhi, Rlo, Wt3h, Wt3l, P, 256, 64, c2_3);
    k_agg<64><<<2048, 256, 0, stream>>>(P, Qhi, Qlo, b3, offs, srcs, sd, dis, S3, Q3s);
    k_bnpar<<<1, 256, 0, stream>>>(S3, Q3s, bn3g, bn3b, sc3, sh3, 64);

    // layer 4: h4 = bn(t3) @ W4 -> P (N x 32 fp16); t4 -> Q planes (32 ch)
    k_smm<64, 32, false><<<NN / 256, 256, 0, stream>>>(Qhi, Qlo, W4, nullptr, P, sc3, sh3);
    k_agg<32><<<2048, 256, 0, stream>>>(P, Qhi, Qlo, b4, offs, srcs, sd, dis, S4, Q4s);
    k_bnpar<<<1, 256, 0, stream>>>(S4, Q4s, bn4g, bn4b, sc4, sh4, 32);

    // gate 1: g1 = bn4(t4) @ gW1 + gb1 -> P (N x 16 fp16)
    k_smm<32, 16, true><<<NN / 256, 256, 0, stream>>>(Qhi, Qlo, gW1, gb1, P, sc4, sh4);
    k_stats16<16><<<NSCAN, 256, 0, stream>>>(P, gS1, gQ1);
    k_bnpar<<<1, 256, 0, stream>>>(gS1, gQ1, gbn1g, gbn1b, gsc1, gsh1, 16);

    // gate 2: g2 = relu(bn(g1)) @ gW2 + gb2 -> g2raw (N, fp32)
    k_gate2<<<NN / 256, 256, 0, stream>>>(P, gsc1, gsh1, gW2, gb2, g2raw);
    k_stats1<<<NSCAN, 256, 0, stream>>>(g2raw, gS2, gQ2);
    k_bnpar<<<1, 256, 0, stream>>>(gS2, gQ2, gbn2g, gbn2b, gsc2, gsh2, 1);

    // pooling + FC + softmax
    k_pool<<<NBATCH / 256, 256, 0, stream>>>(Qhi, Qlo, sc4, sh4, g2raw, gsc2, gsh2, fcW, fcb, out);
}

// Round 7
// 1145.847 us; speedup vs baseline: 1.1836x; 1.1836x over previous
//
#include <hip/hip_runtime.h>

#define NN 114688      // nodes
#define NE 917504      // edges
#define NBATCH 8192    // graphs
#define GSZ 14         // nodes per graph
#define NCLS 10
#define EPSB 1e-5f
#define NSCAN 112      // NN / 1024

typedef unsigned short u16;
typedef short bf16x8 __attribute__((ext_vector_type(8)));
typedef float f32x4 __attribute__((ext_vector_type(4)));
typedef _Float16 h8t __attribute__((ext_vector_type(8)));
typedef unsigned short u16x8 __attribute__((ext_vector_type(8)));

__device__ __forceinline__ float bf2f(u16 u) {
    union { unsigned int i; float f; } v; v.i = ((unsigned int)u) << 16; return v.f;
}
__device__ __forceinline__ u16 f2bf(float f) {
    union { float f; unsigned int i; } v; v.f = f;
    unsigned int i = v.i;
    unsigned int r = i + 0x7FFFu + ((i >> 16) & 1u);   // RNE
    return (u16)(r >> 16);
}
__device__ __forceinline__ void splitbf(float y, u16& h, u16& l) {
    h = f2bf(y);
    l = f2bf(y - bf2f(h));
}

// ---------------- graph preprocessing ----------------
__global__ __launch_bounds__(256) void k_hist(const int* __restrict__ ei, int* __restrict__ counts) {
    int e = blockIdx.x * 256 + threadIdx.x;
    atomicAdd(&counts[ei[NE + e]], 1);
}

__global__ __launch_bounds__(256) void k_scan1(const int* __restrict__ counts, int* __restrict__ bsum) {
    __shared__ int red[256];
    int tid = threadIdx.x;
    int base = blockIdx.x * 1024 + tid * 4;
    int s = counts[base] + counts[base + 1] + counts[base + 2] + counts[base + 3];
    red[tid] = s; __syncthreads();
    for (int o = 128; o > 0; o >>= 1) {
        if (tid < o) red[tid] += red[tid + o];
        __syncthreads();
    }
    if (tid == 0) bsum[blockIdx.x] = red[0];
}

__global__ void k_scan2(int* bsum, int* offs) {
    if (threadIdx.x == 0) {
        int run = 0;
        for (int i = 0; i < NSCAN; i++) { int t = bsum[i]; bsum[i] = run; run += t; }
        offs[NN] = run;
    }
}

__global__ __launch_bounds__(256) void k_scan3(const int* __restrict__ counts, const int* __restrict__ bsum,
                                               int* __restrict__ offs) {
    __shared__ int ss[256];
    int tid = threadIdx.x;
    int base = blockIdx.x * 1024 + tid * 4;
    int v0 = counts[base], v1 = counts[base + 1], v2 = counts[base + 2], v3 = counts[base + 3];
    int ts = v0 + v1 + v2 + v3;
    ss[tid] = ts; __syncthreads();
    for (int o = 1; o < 256; o <<= 1) {
        int add = (tid >= o) ? ss[tid - o] : 0;
        __syncthreads();
        ss[tid] += add;
        __syncthreads();
    }
    int excl = ss[tid] - ts + bsum[blockIdx.x];
    offs[base] = excl;
    offs[base + 1] = excl + v0;
    offs[base + 2] = excl + v0 + v1;
    offs[base + 3] = excl + v0 + v1 + v2;
}

__global__ __launch_bounds__(256) void k_dis_cursor(const int* __restrict__ counts, const int* __restrict__ offs,
                                                    float* __restrict__ dis, int* __restrict__ cursor) {
    int n = blockIdx.x * 256 + threadIdx.x;
    dis[n] = rsqrtf((float)counts[n] + 1.0f);
    cursor[n] = offs[n];
}

__global__ __launch_bounds__(256) void k_scatter(const int* __restrict__ ei, int* __restrict__ cursor,
                                                 int* __restrict__ srcs, float* __restrict__ sd,
                                                 const float* __restrict__ dis) {
    int e = blockIdx.x * 256 + threadIdx.x;
    int d = ei[NE + e], s = ei[e];
    int p = atomicAdd(&cursor[d], 1);
    srcs[p] = s;
    sd[p] = dis[s];
}

// transpose + split fp32 W[K,F] -> bf16 Wh/Wl [F,K] (no affine; layer 1)
__global__ __launch_bounds__(256) void k_tsplit(const float* __restrict__ Wsrc,
                                                u16* __restrict__ Wh, u16* __restrict__ Wl,
                                                int K, int F) {
    int i = blockIdx.x * 256 + threadIdx.x;
    if (i < K * F) {
        int k = i / F, f = i % F;
        u16 h, l; splitbf(Wsrc[i], h, l);
        Wh[f * K + k] = h;
        Wl[f * K + k] = l;
    }
}

// PARALLEL BN-fold, part 1: Wh/Wl[f,k] = split(sc[k]*W[k,f]) — one thread per element
__global__ __launch_bounds__(256) void k_wsplit(const float* __restrict__ W, const float* __restrict__ sc,
                                                u16* __restrict__ Wh, u16* __restrict__ Wl,
                                                int K, int F) {
    int i = blockIdx.x * 256 + threadIdx.x;
    if (i < K * F) {
        int k = i / F, f = i % F;
        u16 h, l; splitbf(sc[k] * W[i], h, l);
        Wh[f * K + k] = h;
        Wl[f * K + k] = l;
    }
}

// PARALLEL BN-fold, part 2: c2[f] = sum_k sh[k]*W[k,f] — one wave per column
__global__ __launch_bounds__(256) void k_wc2(const float* __restrict__ W, const float* __restrict__ sh,
                                             float* __restrict__ c2, int K, int F) {
    int wv = (blockIdx.x * 256 + threadIdx.x) >> 6;
    int lane = threadIdx.x & 63;
    if (wv >= F) return;
    float acc = 0.f;
    for (int k = lane; k < K; k += 64) acc += sh[k] * W[k * F + wv];
#pragma unroll
    for (int o = 1; o < 64; o <<= 1) acc += __shfl_xor(acc, o);
    if (lane == 0) c2[wv] = acc;
}

// ---------------- split MFMA GEMM: C = A @ W' + c2, fp32-grade via bf16x3 ----------------
// AFP32: A is fp32 (layer 1, split at stage). Else A is two exact bf16 planes Ahi/Alo [N][K].
// W pre-split (+BN-folded) bf16 hi/lo [Fout][K]. C2: init acc with per-column constant. C fp16.
template<int BM, int BN, int WCOLS, bool AFP32, bool C2>
__global__ __launch_bounds__(256) void k_gemm(
    const float* __restrict__ Af, const u16* __restrict__ Ahi, const u16* __restrict__ Alo,
    const u16* __restrict__ Wh, const u16* __restrict__ Wl,
    _Float16* __restrict__ C, const int K, const int Fout, const float* __restrict__ c2)
{
    constexpr int AST = 40;                // 32 + 8 pad
    __shared__ u16 Ah[BM][AST], Al[BM][AST];
    __shared__ u16 Bh[BN][AST], Bl[BN][AST];

    const int tid = threadIdx.x;
    const int row0 = blockIdx.y * BM;
    const int col0 = blockIdx.x * BN;

    const int wave = tid >> 6, lane = tid & 63;
    const int mb = (wave / WCOLS) * 64;
    const int nb = (wave % WCOLS) * 64;
    const int lm = lane & 15;
    const int lk = (lane >> 4) * 8;
    const int cb = col0 + nb + lm;

    float c2v[4] = {0.f, 0.f, 0.f, 0.f};
    if constexpr (C2) {
#pragma unroll
        for (int ni = 0; ni < 4; ni++) c2v[ni] = c2[cb + ni * 16];
    }

    f32x4 acc[4][4];
#pragma unroll
    for (int i = 0; i < 4; i++)
#pragma unroll
        for (int j = 0; j < 4; j++)
#pragma unroll
            for (int r = 0; r < 4; r++) acc[i][j][r] = c2v[j];

    const int stg_r = tid >> 3;        // 0..31
    const int stg_c = (tid & 7) * 4;   // 0,4..28

    for (int k0 = 0; k0 < K; k0 += 32) {
        __syncthreads();
#pragma unroll
        for (int p = 0; p < BM / 32; p++) {
            const int r = p * 32 + stg_r;
            if constexpr (AFP32) {
                const float4 v = *(const float4*)(Af + (size_t)(row0 + r) * K + k0 + stg_c);
                float y[4] = {v.x, v.y, v.z, v.w};
                ushort4 hv, lv;
#pragma unroll
                for (int q = 0; q < 4; q++) splitbf(y[q], ((u16*)&hv)[q], ((u16*)&lv)[q]);
                *(ushort4*)&Ah[r][stg_c] = hv;
                *(ushort4*)&Al[r][stg_c] = lv;
            } else {
                *(ushort4*)&Ah[r][stg_c] = *(const ushort4*)(Ahi + (size_t)(row0 + r) * K + k0 + stg_c);
                *(ushort4*)&Al[r][stg_c] = *(const ushort4*)(Alo + (size_t)(row0 + r) * K + k0 + stg_c);
            }
        }
#pragma unroll
        for (int p = 0; p < BN / 32; p++) {
            const int n = p * 32 + stg_r;
            *(ushort4*)&Bh[n][stg_c] = *(const ushort4*)(Wh + (size_t)(col0 + n) * K + k0 + stg_c);
            *(ushort4*)&Bl[n][stg_c] = *(const ushort4*)(Wl + (size_t)(col0 + n) * K + k0 + stg_c);
        }
        __syncthreads();

        bf16x8 ah[4], al[4], bh[4], bl[4];
#pragma unroll
        for (int mi = 0; mi < 4; mi++) {
            ah[mi] = *(const bf16x8*)&Ah[mb + mi * 16 + lm][lk];
            al[mi] = *(const bf16x8*)&Al[mb + mi * 16 + lm][lk];
        }
#pragma unroll
        for (int ni = 0; ni < 4; ni++) {
            bh[ni] = *(const bf16x8*)&Bh[nb + ni * 16 + lm][lk];
            bl[ni] = *(const bf16x8*)&Bl[nb + ni * 16 + lm][lk];
        }
#pragma unroll
        for (int mi = 0; mi < 4; mi++)
#pragma unroll
            for (int ni = 0; ni < 4; ni++) {
                acc[mi][ni] = __builtin_amdgcn_mfma_f32_16x16x32_bf16(al[mi], bh[ni], acc[mi][ni], 0, 0, 0);
                acc[mi][ni] = __builtin_amdgcn_mfma_f32_16x16x32_bf16(ah[mi], bl[ni], acc[mi][ni], 0, 0, 0);
                acc[mi][ni] = __builtin_amdgcn_mfma_f32_16x16x32_bf16(ah[mi], bh[ni], acc[mi][ni], 0, 0, 0);
            }
    }

    const int rb = row0 + mb + (lane >> 4) * 4;
#pragma unroll
    for (int mi = 0; mi < 4; mi++)
#pragma unroll
        for (int ni = 0; ni < 4; ni++)
#pragma unroll
            for (int r = 0; r < 4; r++)
                C[(size_t)(rb + mi * 16 + r) * Fout + cb + ni * 16] = (_Float16)acc[mi][ni][r];
}

// ---------------- aggregation: t = relu(dn*sum(sd_e*h_s) + dn^2*h_n + b), fused BN stats --------
// h fp16 [N][CH]; t written as exact bf16 hi/lo planes [N][CH]. Edge-parallel sub-wavelets,
// 16 ch/lane (32 B); butterfly shfl_xor merges partials. Stats on the exact fp32 value.
template<int CH>
__global__ __launch_bounds__(256) void k_agg(
    const _Float16* __restrict__ h, u16* __restrict__ thi, u16* __restrict__ tlo,
    const float* __restrict__ bias,
    const int* __restrict__ off, const int* __restrict__ srcs, const float* __restrict__ sd,
    const float* __restrict__ dis, float* __restrict__ statS, float* __restrict__ statQ)
{
    constexpr int ECH = 16;            // channels per lane (32B fp16)
    constexpr int LPG = CH / ECH;      // lanes per edge-group
    constexpr int NSUB = 64 / LPG;     // edges in flight per wave
    __shared__ float redS[CH], redQ[CH];
    const int tid = threadIdx.x;
    for (int i = tid; i < CH; i += 256) { redS[i] = 0.f; redQ[i] = 0.f; }
    __syncthreads();

    const int lane = tid & 63;
    const int sub = lane / LPG;
    const int c = (lane % LPG) * ECH;
    const int wid = (blockIdx.x * 256 + tid) >> 6;
    const int nw = (gridDim.x * 256) >> 6;

    float bs[ECH], bq[ECH], bv[ECH];
#pragma unroll
    for (int v = 0; v < ECH; v++) { bs[v] = 0.f; bq[v] = 0.f; bv[v] = bias[c + v]; }

    for (int n = wid; n < NN; n += nw) {
        const int p0 = off[n], p1 = off[n + 1];
        float a[ECH];
#pragma unroll
        for (int v = 0; v < ECH; v++) a[v] = 0.f;

        int p = p0 + sub;
        int s = 0; float w = 0.f;
        if (p < p1) { s = srcs[p]; w = sd[p]; }
        while (p < p1) {
            const int pn = p + NSUB;
            int s2 = 0; float w2 = 0.f;
            if (pn < p1) { s2 = srcs[pn]; w2 = sd[pn]; }   // prefetch next edge
            const _Float16* hr = h + (size_t)s * CH + c;
            h8t hv0 = *(const h8t*)hr;
            h8t hv1 = *(const h8t*)(hr + 8);
#pragma unroll
            for (int v = 0; v < 8; v++) { a[v] += w * (float)hv0[v]; a[v + 8] += w * (float)hv1[v]; }
            s = s2; w = w2; p = pn;
        }
        // merge edge-group partials across sub-wavelets
#pragma unroll
        for (int o = LPG; o < 64; o <<= 1) {
#pragma unroll
            for (int v = 0; v < ECH; v++) a[v] += __shfl_xor(a[v], o);
        }
        if (sub == 0) {
            const float dn = dis[n];
            const float dn2 = dn * dn;
            const _Float16* hr = h + (size_t)n * CH + c;
            h8t hn0 = *(const h8t*)hr;
            h8t hn1 = *(const h8t*)(hr + 8);
            float o16[ECH];
#pragma unroll
            for (int v = 0; v < 8; v++) {
                o16[v] = fmaxf(dn * a[v] + dn2 * (float)hn0[v] + bv[v], 0.f);
                o16[v + 8] = fmaxf(dn * a[v + 8] + dn2 * (float)hn1[v] + bv[v + 8], 0.f);
            }
            u16x8 hv0, lv0, hv1, lv1;
#pragma unroll
            for (int v = 0; v < 8; v++) {
                splitbf(o16[v], ((u16*)&hv0)[v], ((u16*)&lv0)[v]);
                splitbf(o16[v + 8], ((u16*)&hv1)[v], ((u16*)&lv1)[v]);
                bs[v] += o16[v]; bq[v] += o16[v] * o16[v];
                bs[v + 8] += o16[v + 8]; bq[v + 8] += o16[v + 8] * o16[v + 8];
            }
            u16* th = thi + (size_t)n * CH + c;
            u16* tl = tlo + (size_t)n * CH + c;
            *(u16x8*)th = hv0; *(u16x8*)(th + 8) = hv1;
            *(u16x8*)tl = lv0; *(u16x8*)(tl + 8) = lv1;
        }
    }
    if (sub == 0) {
#pragma unroll
        for (int v = 0; v < ECH; v++) { atomicAdd(&redS[c + v], bs[v]); atomicAdd(&redQ[c + v], bq[v]); }
    }
    __syncthreads();
    for (int i = tid; i < CH; i += 256) { atomicAdd(&statS[i], redS[i]); atomicAdd(&statQ[i], redQ[i]); }
}

// ---------------- BN stats -> scale/shift ----------------
__global__ void k_bnpar(const float* __restrict__ S, const float* __restrict__ Q,
                        const float* __restrict__ g, const float* __restrict__ b,
                        float* __restrict__ sc, float* __restrict__ sh, int F) {
    int c = threadIdx.x;
    if (c >= F) return;
    const float invn = 1.0f / (float)NN;
    float mean = S[c] * invn;
    float var = Q[c] * invn - mean * mean;
    float s = g[c] * rsqrtf(fmaxf(var, 0.f) + EPSB);
    sc[c] = s;
    sh[c] = b[c] - mean * s;
}

// ---------------- small dense layer: C[N,F] = affine(A)[N,K] @ W[K,F] (+bias) ----------------
// A = bf16 hi/lo planes, C fp16, fp32 compute.
template<int K, int F, bool BIAS>
__global__ __launch_bounds__(256) void k_smm(
    const u16* __restrict__ Ahi, const u16* __restrict__ Alo,
    const float* __restrict__ Wf, const float* __restrict__ bias,
    _Float16* __restrict__ C, const float* __restrict__ sc, const float* __restrict__ sh)
{
    __shared__ float Wl[K * F];
    __shared__ float scl[K], shl[K], bl[F];
    const int tid = threadIdx.x;
    for (int i = tid; i < K * F; i += 256) Wl[i] = Wf[i];
    if (tid < K) { scl[tid] = sc[tid]; shl[tid] = sh[tid]; }
    if (tid < F) {
        bl[tid] = 0.f;
        if constexpr (BIAS) bl[tid] = bias[tid];
    }
    __syncthreads();
    const int n = blockIdx.x * 256 + tid;
    float acc[F];
#pragma unroll
    for (int f = 0; f < F; f++) acc[f] = bl[f];
    const u16* ah = Ahi + (size_t)n * K;
    const u16* al = Alo + (size_t)n * K;
    for (int k = 0; k < K; k += 4) {
        ushort4 hv = *(const ushort4*)(ah + k);
        ushort4 lv = *(const ushort4*)(al + k);
        float y0 = (bf2f(hv.x) + bf2f(lv.x)) * scl[k] + shl[k];
        float y1 = (bf2f(hv.y) + bf2f(lv.y)) * scl[k + 1] + shl[k + 1];
        float y2 = (bf2f(hv.z) + bf2f(lv.z)) * scl[k + 2] + shl[k + 2];
        float y3 = (bf2f(hv.w) + bf2f(lv.w)) * scl[k + 3] + shl[k + 3];
#pragma unroll
        for (int f = 0; f < F; f += 4) {
            float4 w0 = *(const float4*)&Wl[k * F + f];
            float4 w1 = *(const float4*)&Wl[(k + 1) * F + f];
            float4 w2 = *(const float4*)&Wl[(k + 2) * F + f];
            float4 w3 = *(const float4*)&Wl[(k + 3) * F + f];
            acc[f + 0] += y0 * w0.x + y1 * w1.x + y2 * w2.x + y3 * w3.x;
            acc[f + 1] += y0 * w0.y + y1 * w1.y + y2 * w2.y + y3 * w3.y;
            acc[f + 2] += y0 * w0.z + y1 * w1.z + y2 * w2.z + y3 * w3.z;
            acc[f + 3] += y0 * w0.w + y1 * w1.w + y2 * w2.w + y3 * w3.w;
        }
    }
    _Float16* cr = C + (size_t)n * F;
#pragma unroll
    for (int f = 0; f < F; f++) cr[f] = (_Float16)acc[f];
}

// ---------------- per-channel stats over [NN, F] fp16 ----------------
template<int F>
__global__ __launch_bounds__(256) void k_stats16(const _Float16* __restrict__ A,
                                                 float* __restrict__ S, float* __restrict__ Q) {
    __shared__ float redS[F], redQ[F];
    const int tid = threadIdx.x;
    for (int i = tid; i < F; i += 256) { redS[i] = 0.f; redQ[i] = 0.f; }
    __syncthreads();
    const int g = blockIdx.x * 256 + tid;
    const int c = g % F;
    const int step = (gridDim.x * 256) / F;
    float s = 0.f, q = 0.f;
    for (int r = g / F; r < NN; r += step) {
        float v = (float)A[(size_t)r * F + c];
        s += v; q += v * v;
    }
    atomicAdd(&redS[c], s); atomicAdd(&redQ[c], q);
    __syncthreads();
    for (int i = tid; i < F; i += 256) { atomicAdd(&S[i], redS[i]); atomicAdd(&Q[i], redQ[i]); }
}

// stats over fp32 [NN] vector
__global__ __launch_bounds__(256) void k_stats1(const float* __restrict__ A,
                                                float* __restrict__ S, float* __restrict__ Q) {
    __shared__ float redS[1], redQ[1];
    const int tid = threadIdx.x;
    if (tid == 0) { redS[0] = 0.f; redQ[0] = 0.f; }
    __syncthreads();
    const int g = blockIdx.x * 256 + tid;
    const int step = gridDim.x * 256;
    float s = 0.f, q = 0.f;
    for (int r = g; r < NN; r += step) {
        float v = A[r];
        s += v; q += v * v;
    }
    atomicAdd(&redS[0], s); atomicAdd(&redQ[0], q);
    __syncthreads();
    if (tid == 0) { atomicAdd(&S[0], redS[0]); atomicAdd(&Q[0], redQ[0]); }
}

// ---------------- gate layer 2: g2 = relu(bn1(g1)) @ gW2 + gb2 ----------------
__global__ __launch_bounds__(256) void k_gate2(const _Float16* __restrict__ g1,
                                               const float* __restrict__ sc, const float* __restrict__ sh,
                                               const float* __restrict__ w2, const float* __restrict__ b2,
                                               float* __restrict__ g2) {
    __shared__ float wl[16], scl[16], shl[16], b2l[1];
    const int tid = threadIdx.x;
    if (tid < 16) { wl[tid] = w2[tid]; scl[tid] = sc[tid]; shl[tid] = sh[tid]; }
    if (tid == 0) b2l[0] = b2[0];
    __syncthreads();
    const int n = blockIdx.x * 256 + tid;
    const _Float16* r = g1 + (size_t)n * 16;
    float acc = b2l[0];
#pragma unroll
    for (int k = 0; k < 16; k++) {
        float y = fmaxf((float)r[k] * scl[k] + shl[k], 0.f);
        acc += y * wl[k];
    }
    g2[n] = acc;
}

// ---------------- segment softmax + pooling + FC + softmax ----------------
__global__ __launch_bounds__(256) void k_pool(const u16* __restrict__ t4hi, const u16* __restrict__ t4lo,
                                              const float* __restrict__ sc4, const float* __restrict__ sh4,
                                              const float* __restrict__ g2,
                                              const float* __restrict__ gsc2, const float* __restrict__ gsh2,
                                              const float* __restrict__ fcW, const float* __restrict__ fcb,
                                              float* __restrict__ out) {
    __shared__ float fw[32 * NCLS], fbl[NCLS], sc4l[32], sh4l[32];
    const int tid = threadIdx.x;
    for (int i = tid; i < 32 * NCLS; i += 256) fw[i] = fcW[i];
    if (tid < NCLS) fbl[tid] = fcb[tid];
    if (tid < 32) { sc4l[tid] = sc4[tid]; sh4l[tid] = sh4[tid]; }
    __syncthreads();
    const int b = blockIdx.x * 256 + tid;
    const float s2 = gsc2[0], h2 = gsh2[0];
    const int base = b * GSZ;

    float gv[GSZ];
    float m = -1e30f;
#pragma unroll
    for (int i = 0; i < GSZ; i++) {
        float v = fmaxf(g2[base + i] * s2 + h2, 0.f);
        gv[i] = v; m = fmaxf(m, v);
    }
    float ssum = 0.f;
#pragma unroll
    for (int i = 0; i < GSZ; i++) { float e = __expf(gv[i] - m); gv[i] = e; ssum += e; }
    const float inv = 1.0f / ssum;

    float pooled[32];
#pragma unroll
    for (int c = 0; c < 32; c++) pooled[c] = 0.f;
#pragma unroll
    for (int i = 0; i < GSZ; i++) {
        const float a = gv[i] * inv;
        const u16* th = t4hi + (size_t)(base + i) * 32;
        const u16* tl = t4lo + (size_t)(base + i) * 32;
#pragma unroll
        for (int c = 0; c < 32; c += 4) {
            ushort4 hv = *(const ushort4*)(th + c);
            ushort4 lv = *(const ushort4*)(tl + c);
            pooled[c + 0] += a * ((bf2f(hv.x) + bf2f(lv.x)) * sc4l[c + 0] + sh4l[c + 0]);
            pooled[c + 1] += a * ((bf2f(hv.y) + bf2f(lv.y)) * sc4l[c + 1] + sh4l[c + 1]);
            pooled[c + 2] += a * ((bf2f(hv.z) + bf2f(lv.z)) * sc4l[c + 2] + sh4l[c + 2]);
            pooled[c + 3] += a * ((bf2f(hv.w) + bf2f(lv.w)) * sc4l[c + 3] + sh4l[c + 3]);
        }
    }
    float lg[NCLS];
    float mx = -1e30f;
#pragma unroll
    for (int j = 0; j < NCLS; j++) {
        float a = fbl[j];
#pragma unroll
        for (int c = 0; c < 32; c++) a += pooled[c] * fw[c * NCLS + j];
        lg[j] = a; mx = fmaxf(mx, a);
    }
    float es = 0.f;
#pragma unroll
    for (int j = 0; j < NCLS; j++) { float e = __expf(lg[j] - mx); lg[j] = e; es += e; }
    const float iv = 1.0f / es;
#pragma unroll
    for (int j = 0; j < NCLS; j++) out[b * NCLS + j] = lg[j] * iv;
}

// ---------------- host ----------------
extern "C" void kernel_launch(void* const* d_in, const int* in_sizes, int n_in,
                              void* d_out, int out_size, void* d_ws, size_t ws_size,
                              hipStream_t stream) {
    (void)in_sizes; (void)n_in; (void)out_size; (void)ws_size;
    const float* x    = (const float*)d_in[0];
    const int*   ei   = (const int*)d_in[1];
    const float* W1   = (const float*)d_in[2];
    const float* b1   = (const float*)d_in[3];
    const float* bn1g = (const float*)d_in[4];
    const float* bn1b = (const float*)d_in[5];
    const float* W2   = (const float*)d_in[6];
    const float* b2   = (const float*)d_in[7];
    const float* bn2g = (const float*)d_in[8];
    const float* bn2b = (const float*)d_in[9];
    const float* W3   = (const float*)d_in[10];
    const float* b3   = (const float*)d_in[11];
    const float* bn3g = (const float*)d_in[12];
    const float* bn3b = (const float*)d_in[13];
    const float* W4   = (const float*)d_in[14];
    const float* b4   = (const float*)d_in[15];
    const float* bn4g = (const float*)d_in[16];
    const float* bn4b = (const float*)d_in[17];
    const float* gW1  = (const float*)d_in[18];
    const float* gb1  = (const float*)d_in[19];
    const float* gbn1g = (const float*)d_in[20];
    const float* gbn1b = (const float*)d_in[21];
    const float* gW2  = (const float*)d_in[22];
    const float* gb2  = (const float*)d_in[23];
    const float* gbn2g = (const float*)d_in[24];
    const float* gbn2b = (const float*)d_in[25];
    const float* fcW  = (const float*)d_in[26];
    const float* fcb  = (const float*)d_in[27];
    float* out = (float*)d_out;

    char* base = (char*)d_ws;
    size_t off_ = 0;
    auto carve = [&](size_t bytes) -> char* {
        char* p = base + off_;
        off_ = (off_ + bytes + 255) & ~(size_t)255;
        return p;
    };
    int*   counts = (int*)carve((size_t)NN * 4);
    float* stats  = (float*)carve(994 * 4);
    const size_t zero_bytes = off_;
    int*   offs   = (int*)carve((size_t)(NN + 1) * 4);
    int*   cursor = (int*)carve((size_t)NN * 4);
    int*   srcs   = (int*)carve((size_t)NE * 4);
    float* sd     = (float*)carve((size_t)NE * 4);
    float* dis    = (float*)carve((size_t)NN * 4);
    int*   bsum   = (int*)carve(NSCAN * 4);
    float* pars   = (float*)carve(994 * 4);
    u16*   Wt1h   = (u16*)carve(512 * 128 * 2);
    u16*   Wt1l   = (u16*)carve(512 * 128 * 2);
    u16*   Wt2h   = (u16*)carve(128 * 256 * 2);
    u16*   Wt2l   = (u16*)carve(128 * 256 * 2);
    u16*   Wt3h   = (u16*)carve(256 * 64 * 2);
    u16*   Wt3l   = (u16*)carve(256 * 64 * 2);
    float* c2_2   = (float*)carve(256 * 4);
    float* c2_3   = (float*)carve(64 * 4);
    float* g2raw  = (float*)carve((size_t)NN * 4);
    _Float16* P   = (_Float16*)carve((size_t)NN * 256 * 2);   // h buffer (fp16, up to 256 ch)
    u16*   Qhi    = (u16*)carve((size_t)NN * 128 * 2);        // t planes (<=128 ch)
    u16*   Qlo    = (u16*)carve((size_t)NN * 128 * 2);
    u16*   Rhi    = (u16*)carve((size_t)NN * 256 * 2);        // t2 planes (256 ch)
    u16*   Rlo    = (u16*)carve((size_t)NN * 256 * 2);
    // total ~245 MB (< proven-available 262 MB)

    float* S1 = stats;      float* Q1s = S1 + 128;
    float* S2 = Q1s + 128;  float* Q2s = S2 + 256;
    float* S3 = Q2s + 256;  float* Q3s = S3 + 64;
    float* S4 = Q3s + 64;   float* Q4s = S4 + 32;
    float* gS1 = Q4s + 32;  float* gQ1 = gS1 + 16;
    float* gS2 = gQ1 + 16;  float* gQ2 = gS2 + 1;

    float* sc1 = pars;      float* sh1 = sc1 + 128;
    float* sc2 = sh1 + 128; float* sh2 = sc2 + 256;
    float* sc3 = sh2 + 256; float* sh3 = sc3 + 64;
    float* sc4 = sh3 + 64;  float* sh4 = sc4 + 32;
    float* gsc1 = sh4 + 32; float* gsh1 = gsc1 + 16;
    float* gsc2 = gsh1 + 16; float* gsh2 = gsc2 + 1;

    hipMemsetAsync(d_ws, 0, zero_bytes, stream);

    k_hist<<<NE / 256, 256, 0, stream>>>(ei, counts);
    k_scan1<<<NSCAN, 256, 0, stream>>>(counts, bsum);
    k_scan2<<<1, 64, 0, stream>>>(bsum, offs);
    k_scan3<<<NSCAN, 256, 0, stream>>>(counts, bsum, offs);
    k_dis_cursor<<<NN / 256, 256, 0, stream>>>(counts, offs, dis, cursor);
    k_scatter<<<NE / 256, 256, 0, stream>>>(ei, cursor, srcs, sd, dis);
    k_tsplit<<<(512 * 128 + 255) / 256, 256, 0, stream>>>(W1, Wt1h, Wt1l, 512, 128);

    // layer 1: h1 = x @ W1 -> P (N x 128 fp16); t1 -> Q planes
    k_gemm<128, 128, 2, true, false><<<dim3(1, NN / 128), 256, 0, stream>>>(
        x, nullptr, nullptr, Wt1h, Wt1l, P, 512, 128, nullptr);
    k_agg<128><<<2048, 256, 0, stream>>>(P, Qhi, Qlo, b1, offs, srcs, sd, dis, S1, Q1s);
    k_bnpar<<<1, 256, 0, stream>>>(S1, Q1s, bn1g, bn1b, sc1, sh1, 128);

    // layer 2 (full width, BN folded into W2): h2 = t1 @ W2' + c2 -> P (N x 256); t2 -> R planes
    k_wsplit<<<(128 * 256 + 255) / 256, 256, 0, stream>>>(W2, sc1, Wt2h, Wt2l, 128, 256);
    k_wc2<<<(256 * 64 + 255) / 256, 256, 0, stream>>>(W2, sh1, c2_2, 128, 256);
    k_gemm<128, 128, 2, false, true><<<dim3(2, NN / 128), 256, 0, stream>>>(
        nullptr, Qhi, Qlo, Wt2h, Wt2l, P, 128, 256, c2_2);
    k_agg<256><<<2048, 256, 0, stream>>>(P, Rhi, Rlo, b2, offs, srcs, sd, dis, S2, Q2s);
    k_bnpar<<<1, 256, 0, stream>>>(S2, Q2s, bn2g, bn2b, sc2, sh2, 256);

    // layer 3 (BN folded into W3): h3 = t2 @ W3' + c2 -> P (N x 64); t3 -> Q planes
    k_wsplit<<<(256 * 64 + 255) / 256, 256, 0, stream>>>(W3, sc2, Wt3h, Wt3l, 256, 64);
    k_wc2<<<(64 * 64 + 255) / 256, 256, 0, stream>>>(W3, sh2, c2_3, 256, 64);
    k_gemm<256, 64, 1, false, true><<<dim3(1, NN / 256), 256, 0, stream>>>(
        nullptr, Rhi, Rlo, Wt3h, Wt3l, P, 256, 64, c2_3);
    k_agg<64><<<2048, 256, 0, stream>>>(P, Qhi, Qlo, b3, offs, srcs, sd, dis, S3, Q3s);
    k_bnpar<<<1, 256, 0, stream>>>(S3, Q3s, bn3g, bn3b, sc3, sh3, 64);

    // layer 4: h4 = bn(t3) @ W4 -> P (N x 32 fp16); t4 -> Q planes (32 ch)
    k_smm<64, 32, false><<<NN / 256, 256, 0, stream>>>(Qhi, Qlo, W4, nullptr, P, sc3, sh3);
    k_agg<32><<<2048, 256, 0, stream>>>(P, Qhi, Qlo, b4, offs, srcs, sd, dis, S4, Q4s);
    k_bnpar<<<1, 256, 0, stream>>>(S4, Q4s, bn4g, bn4b, sc4, sh4, 32);

    // gate 1: g1 = bn4(t4) @ gW1 + gb1 -> P (N x 16 fp16)
    k_smm<32, 16, true><<<NN / 256, 256, 0, stream>>>(Qhi, Qlo, gW1, gb1, P, sc4, sh4);
    k_stats16<16><<<NSCAN, 256, 0, stream>>>(P, gS1, gQ1);
    k_bnpar<<<1, 256, 0, stream>>>(gS1, gQ1, gbn1g, gbn1b, gsc1, gsh1, 16);

    // gate 2: g2 = relu(bn(g1)) @ gW2 + gb2 -> g2raw (N, fp32)
    k_gate2<<<NN / 256, 256, 0, stream>>>(P, gsc1, gsh1, gW2, gb2, g2raw);
    k_stats1<<<NSCAN, 256, 0, stream>>>(g2raw, gS2, gQ2);
    k_bnpar<<<1, 256, 0, stream>>>(gS2, gQ2, gbn2g, gbn2b, gsc2, gsh2, 1);

    // pooling + FC + softmax
    k_pool<<<NBATCH / 256, 256, 0, stream>>>(Qhi, Qlo, sc4, sh4, g2raw, gsc2, gsh2, fcW, fcb, out);
}